// Round 1
// baseline (759.199 us; speedup 1.0000x reference)
//
#include <hip/hip_runtime.h>
#include <math.h>

#define HH 384
#define WW 384
#define NPIX (HH*WW)
#define CC 48
#define TS 16
#define HS 18
#define HP 324          // 18*18
#define CHUNK 1296      // 324*4, floats per channel-chunk plane

// float -> bf16 (RNE)
__device__ __forceinline__ ushort f2bf(float f) {
    uint x = __float_as_uint(f);
    uint r = (x + 0x7FFFu + ((x >> 16) & 1u)) >> 16;
    return (ushort)r;
}

// ---------------------------------------------------------------------------
// K1: fused pointwise(48->48 / 48->96) + depthwise3x3 producing q,k,v.
//     v is written to d_out. Norms + per-head Gram accumulated via atomics.
// LDS layout: chunk-major [12][324][4] floats (62208 B) -> conflict-light,
// 16B-aligned float4 access. Reused (aliased) as bf16 [96][260] for Gram.
// ---------------------------------------------------------------------------
__global__ __launch_bounds__(256, 2) void k1_qkv(
    const float* __restrict__ img, const float* __restrict__ evs,
    const float* __restrict__ Wq1, const float* __restrict__ Wq2,
    const float* __restrict__ Wkv1, const float* __restrict__ Wkv2,
    float* __restrict__ vout, float* __restrict__ acc_ws)
{
    __shared__ float s_tile[12 * CHUNK];   // 62208 B
    const int tid = threadIdx.x;
    const int b = blockIdx.z;
    const int x0 = blockIdx.x * TS - 1, y0 = blockIdx.y * TS - 1;
    float* nq   = acc_ws;          // [2][48] sum q^2
    float* nk   = acc_ws + 96;     // [2][48] sum k^2
    float* gram = acc_ws + 192;    // [2][48][6]

    auto stage = [&](const float* __restrict__ src) {
        #pragma unroll 4
        for (int e = tid; e < HP * CC; e += 256) {
            int ci = e / HP;
            int p  = e - ci * HP;
            int yy = y0 + p / HS;
            int xx = x0 + p % HS;
            float val = 0.f;
            if ((unsigned)yy < HH && (unsigned)xx < WW)
                val = src[ci * NPIX + yy * WW + xx];
            s_tile[(ci >> 2) * CHUNK + p * 4 + (ci & 3)] = val;
        }
    };

    // pointwise 48 -> 48 over halo tile, in place (per-pixel: regs in, regs out)
    auto pw = [&](const float* __restrict__ w) {
        for (int p = tid; p < HP; p += 256) {
            float in[CC];
            #pragma unroll
            for (int i = 0; i < CC / 4; i++)
                *(float4*)&in[i * 4] = *(const float4*)&s_tile[i * CHUNK + p * 4];
            #pragma unroll 1
            for (int c = 0; c < CC; c += 2) {
                float a0 = 0.f, a1 = 0.f, b0 = 0.f, b1 = 0.f;
                #pragma unroll
                for (int ci = 0; ci < CC; ci += 2) {
                    a0 = fmaf(w[c * CC + ci],           in[ci],     a0);
                    a1 = fmaf(w[c * CC + ci + 1],       in[ci + 1], a1);
                    b0 = fmaf(w[(c + 1) * CC + ci],     in[ci],     b0);
                    b1 = fmaf(w[(c + 1) * CC + ci + 1], in[ci + 1], b1);
                }
                s_tile[(c >> 2) * CHUNK + p * 4 + (c & 3)]       = a0 + a1;
                s_tile[((c + 1) >> 2) * CHUNK + p * 4 + ((c + 1) & 3)] = b0 + b1;
            }
        }
    };

    // depthwise 3x3 (center depth slice of 3x3x3), w stride 27, offset +9
    auto dw = [&](const float* __restrict__ w, float (&o)[CC]) {
        const int oy = tid >> 4, ox = tid & 15;
        const int hp = (oy + 1) * HS + (ox + 1);
        #pragma unroll
        for (int c = 0; c < CC; c += 4) {
            float ax = 0.f, ay = 0.f, az = 0.f, aw = 0.f;
            #pragma unroll
            for (int t = 0; t < 9; t++) {
                const int ky = t / 3, kx = t % 3;
                const int np = hp + (ky - 1) * HS + (kx - 1);
                float4 pv = *(const float4*)&s_tile[(c >> 2) * CHUNK + np * 4];
                ax = fmaf(w[(c + 0) * 27 + 9 + t], pv.x, ax);
                ay = fmaf(w[(c + 1) * 27 + 9 + t], pv.y, ay);
                az = fmaf(w[(c + 2) * 27 + 9 + t], pv.z, az);
                aw = fmaf(w[(c + 3) * 27 + 9 + t], pv.w, aw);
            }
            o[c] = ax; o[c + 1] = ay; o[c + 2] = az; o[c + 3] = aw;
        }
    };

    float q[CC], k[CC];

    // ---- q path ----
    stage(evs + (size_t)b * CC * NPIX);
    __syncthreads();
    pw(Wq1);
    __syncthreads();
    dw(Wq2, q);
    __syncthreads();

    // ---- k path ----
    stage(img + (size_t)b * CC * NPIX);
    __syncthreads();
    pw(Wkv1);                 // rows 0..47 of Wkv1 -> k
    __syncthreads();
    dw(Wkv2, k);
    __syncthreads();

    // ---- reduction: norms + Gram via bf16 LDS transpose + parallel dots ----
    ushort* s_qk = (ushort*)s_tile;       // rows [96][260] (49920 B < 62208 B)
    #pragma unroll
    for (int c = 0; c < CC; c++) {
        s_qk[c * 260 + tid]        = f2bf(q[c]);
        s_qk[(CC + c) * 260 + tid] = f2bf(k[c]);
    }
    __syncthreads();

    for (int j = tid; j < 384; j += 256) {
        int ra, rb;
        if (j < 96) { ra = j; rb = j; }      // j<48: q.q (norm), j<96: k.k (row 48+)
        else {
            int jc = j - 96;
            int c1 = jc / 6;
            int jj = jc - c1 * 6;
            ra = c1;
            rb = CC + (c1 / 6) * 6 + jj;
        }
        const ushort* A  = s_qk + ra * 260;
        const ushort* Bp = s_qk + rb * 260;
        float s = 0.f;
        #pragma unroll 8
        for (int i = 0; i < 256; i += 2) {
            uint a  = *(const uint*)(A + i);
            uint bb = *(const uint*)(Bp + i);
            float axx = __uint_as_float(a << 16);
            float ayy = __uint_as_float(a & 0xFFFF0000u);
            float bxx = __uint_as_float(bb << 16);
            float byy = __uint_as_float(bb & 0xFFFF0000u);
            s = fmaf(axx, bxx, s);
            s = fmaf(ayy, byy, s);
        }
        float* dst = (j < 48) ? (nq + b * CC + j)
                   : (j < 96) ? (nk + b * CC + (j - 48))
                              : (gram + b * 288 + (j - 96));
        atomicAdd(dst, s);
    }
    __syncthreads();

    // ---- v path (re-stage img; rows 48..95 of Wkv1/Wkv2) ----
    stage(img + (size_t)b * CC * NPIX);
    __syncthreads();
    pw(Wkv1 + CC * CC);
    __syncthreads();
    float v[CC];
    dw(Wkv2 + CC * 27, v);

    const int oy = tid >> 4, ox = tid & 15;
    const int gy = blockIdx.y * TS + oy, gx = blockIdx.x * TS + ox;
    #pragma unroll
    for (int c = 0; c < CC; c++)
        vout[((size_t)b * CC + c) * NPIX + gy * WW + gx] = v[c];
}

// ---------------------------------------------------------------------------
// K2: logits -> softmax -> fold Wout => M[b][co][c2]  (tiny, one block)
// ---------------------------------------------------------------------------
__global__ void k2_attn(const float* __restrict__ acc_ws,
                        const float* __restrict__ Wout,
                        const float* __restrict__ temp,
                        float* __restrict__ M)
{
    __shared__ float s_attn[2 * 8 * 6 * 6];
    const int tid = threadIdx.x;
    const float* nq   = acc_ws;
    const float* nk   = acc_ws + 96;
    const float* gram = acc_ws + 192;

    if (tid < 16) {
        const int b = tid >> 3, h = tid & 7;
        const float t = temp[h];
        float qn[6], kn[6], L[6][6];
        #pragma unroll
        for (int i = 0; i < 6; i++) {
            qn[i] = fmaxf(sqrtf(nq[b * CC + h * 6 + i]), 1e-12f);
            kn[i] = fmaxf(sqrtf(nk[b * CC + h * 6 + i]), 1e-12f);
        }
        #pragma unroll
        for (int i = 0; i < 6; i++)
            #pragma unroll
            for (int jj = 0; jj < 6; jj++)
                L[i][jj] = gram[b * 288 + (h * 6 + i) * 6 + jj] / (qn[i] * kn[jj]) * t;
        #pragma unroll
        for (int i = 0; i < 6; i++) {
            float m = L[i][0];
            #pragma unroll
            for (int jj = 1; jj < 6; jj++) m = fmaxf(m, L[i][jj]);
            float e[6], ssum = 0.f;
            #pragma unroll
            for (int jj = 0; jj < 6; jj++) { e[jj] = expf(L[i][jj] - m); ssum += e[jj]; }
            #pragma unroll
            for (int jj = 0; jj < 6; jj++)
                s_attn[((b * 8 + h) * 6 + i) * 6 + jj] = e[jj] / ssum;
        }
    }
    __syncthreads();

    for (int e = tid; e < 2 * CC * CC; e += 256) {
        const int b  = e / (CC * CC);
        const int r  = e - b * CC * CC;
        const int co = r / CC;
        const int c2 = r - co * CC;
        const int h2 = c2 / 6, j2 = c2 - h2 * 6;
        float s = 0.f;
        #pragma unroll
        for (int i = 0; i < 6; i++)
            s += Wout[co * CC + h2 * 6 + i] * s_attn[((b * 8 + h2) * 6 + i) * 6 + j2];
        M[e] = s;
    }
}

// ---------------------------------------------------------------------------
// K3: in-place per-pixel out = M @ v  (v lives in d_out)
// ---------------------------------------------------------------------------
__global__ __launch_bounds__(256) void k3_out(float* __restrict__ out,
                                              const float* __restrict__ M)
{
    const int b = blockIdx.y;
    const int pix = blockIdx.x * 256 + threadIdx.x;
    const float* Mb = M + b * CC * CC;
    float* base = out + (size_t)b * CC * NPIX + pix;

    float v[CC];
    #pragma unroll
    for (int c = 0; c < CC; c++) v[c] = base[(size_t)c * NPIX];

    #pragma unroll 1
    for (int co = 0; co < CC; co += 2) {
        float a0 = 0.f, a1 = 0.f, b0 = 0.f, b1 = 0.f;
        #pragma unroll
        for (int ci = 0; ci < CC; ci += 2) {
            a0 = fmaf(Mb[co * CC + ci],           v[ci],     a0);
            a1 = fmaf(Mb[co * CC + ci + 1],       v[ci + 1], a1);
            b0 = fmaf(Mb[(co + 1) * CC + ci],     v[ci],     b0);
            b1 = fmaf(Mb[(co + 1) * CC + ci + 1], v[ci + 1], b1);
        }
        base[(size_t)co * NPIX]       = a0 + a1;
        base[(size_t)(co + 1) * NPIX] = b0 + b1;
    }
}

extern "C" void kernel_launch(void* const* d_in, const int* in_sizes, int n_in,
                              void* d_out, int out_size, void* d_ws, size_t ws_size,
                              hipStream_t stream)
{
    const float* img  = (const float*)d_in[0];
    const float* evs  = (const float*)d_in[1];
    const float* Wq1  = (const float*)d_in[2];
    const float* Wq2  = (const float*)d_in[3];
    const float* Wkv1 = (const float*)d_in[4];
    const float* Wkv2 = (const float*)d_in[5];
    const float* Wout = (const float*)d_in[6];
    const float* temp = (const float*)d_in[7];
    float* out = (float*)d_out;
    float* ws  = (float*)d_ws;

    // zero norm/gram accumulators (first 768 floats of ws)
    hipMemsetAsync(ws, 0, 768 * sizeof(float), stream);

    k1_qkv<<<dim3(WW / TS, HH / TS, 2), 256, 0, stream>>>(
        img, evs, Wq1, Wq2, Wkv1, Wkv2, out, ws);
    k2_attn<<<1, 256, 0, stream>>>(ws, Wout, temp, ws + 768);
    k3_out<<<dim3(NPIX / 256, 2), 256, 0, stream>>>(out, ws + 768);
}

// Round 2
// 471.390 us; speedup vs baseline: 1.6106x; 1.6106x over previous
//
#include <hip/hip_runtime.h>
#include <math.h>

#define HH 384
#define WW 384
#define NPIX (HH*WW)
#define CC 48
#define TS 16
#define HS 18
#define HP 324          // 18*18 halo pixels
#define NROW 336        // padded to 21 MFMA n-tiles
#define SR 48           // ushort (bf16) per pixel row

typedef __attribute__((ext_vector_type(8))) short bf16x8;
typedef __attribute__((ext_vector_type(4))) float f32x4;

// float -> bf16 (RNE)
__device__ __forceinline__ ushort f2bf(float f) {
    uint x = __float_as_uint(f);
    return (ushort)((x + 0x7FFFu + ((x >> 16) & 1u)) >> 16);
}

// ---------------------------------------------------------------------------
// K1: bf16 LDS staging; pointwise conv via MFMA 16x16x32; depthwise 3x3 VALU;
//     img staged ONCE (k and v pw reuse resident tile); Gram via bf16 dots.
// LDS: s_in[336][48] bf16 (32256 B) + s_x1[336][48] bf16 (32256 B) = 64512 B,
// aliased as s_qk[96][260] bf16 (49920 B) for the Gram reduction.
// ---------------------------------------------------------------------------
__global__ __launch_bounds__(256, 2) void k1_qkv(
    const float* __restrict__ img, const float* __restrict__ evs,
    const float* __restrict__ Wq1, const float* __restrict__ Wq2,
    const float* __restrict__ Wkv1, const float* __restrict__ Wkv2,
    float* __restrict__ vout, float* __restrict__ acc_ws)
{
    __shared__ ushort s_mem[2 * NROW * SR];   // 64512 B
    ushort* s_in = s_mem;
    ushort* s_x1 = s_mem + NROW * SR;

    const int tid = threadIdx.x;
    const int wave = tid >> 6, lane = tid & 63;
    const int b = blockIdx.z;
    const int x0 = blockIdx.x * TS - 1, y0 = blockIdx.y * TS - 1;

    float* nq   = acc_ws;          // [2][48] sum q^2
    float* nk   = acc_ws + 96;     // [2][48] sum k^2
    float* gram = acc_ws + 192;    // [2][48][6]

    // zero pad rows 324..335 of s_in (keeps NaN out of MFMA B overflow reads)
    {
        uint* z = (uint*)(s_in + HP * SR);
        for (int i = tid; i < (NROW - HP) * SR / 2; i += 256) z[i] = 0;
    }

    auto stage = [&](const float* __restrict__ src) {
        for (int e = tid; e < HP * CC; e += 256) {
            int ci = e / HP;
            int p  = e - ci * HP;
            int yy = y0 + p / HS;
            int xx = x0 + p % HS;
            float val = 0.f;
            if ((unsigned)yy < HH && (unsigned)xx < WW)
                val = src[ci * NPIX + yy * WW + xx];
            s_in[p * SR + ci] = f2bf(val);
        }
    };

    // pointwise conv via MFMA: x1[ch 0..47][pix] = W[ch][0..47] @ in[..][pix]
    // A-frag: lane row = ch (lane&15 + 16*mt), k = ks*32 + (lane>>4)*8 + j
    // B-frag: lane col = pix (lane&15 + 16*nt), same k -> b128 from s_in[pix][k0]
    // D: col = pix (lane&15), rows = 4 consecutive ch -> packed b64 to s_x1
    auto pw = [&](const float* __restrict__ W) {
        bf16x8 Af[3][2];
        #pragma unroll
        for (int mt = 0; mt < 3; mt++) {
            const int ch = mt * 16 + (lane & 15);
            #pragma unroll
            for (int ks = 0; ks < 2; ks++) {
                const int k0 = ks * 32 + (lane >> 4) * 8;
                bf16x8 a;
                if (k0 < CC) {
                    const float* p = W + ch * CC + k0;
                    #pragma unroll
                    for (int j = 0; j < 8; j++) a[j] = (short)f2bf(p[j]);
                } else {
                    #pragma unroll
                    for (int j = 0; j < 8; j++) a[j] = 0;
                }
                Af[mt][ks] = a;
            }
        }
        for (int nt = wave; nt < 21; nt += 4) {
            const int pix = nt * 16 + (lane & 15);
            const ushort* rp = s_in + pix * SR;
            bf16x8 b0 = *(const bf16x8*)(rp + (lane >> 4) * 8);
            bf16x8 b1 = *(const bf16x8*)(rp + 32 + (lane >> 4) * 8); // k>=48 lanes read
                                                                      // garbage; A=0 there
            #pragma unroll
            for (int mt = 0; mt < 3; mt++) {
                f32x4 acc = {0.f, 0.f, 0.f, 0.f};
                acc = __builtin_amdgcn_mfma_f32_16x16x32_bf16(Af[mt][0], b0, acc, 0, 0, 0);
                acc = __builtin_amdgcn_mfma_f32_16x16x32_bf16(Af[mt][1], b1, acc, 0, 0, 0);
                ushort4 pk = { f2bf(acc[0]), f2bf(acc[1]), f2bf(acc[2]), f2bf(acc[3]) };
                *(ushort4*)(s_x1 + pix * SR + mt * 16 + (lane >> 4) * 4) = pk;
            }
        }
    };

    // depthwise 3x3 (center depth slice), reads bf16 x1, fp32 accumulate
    auto dw = [&](const float* __restrict__ w, float (&o)[CC]) {
        const int oy = tid >> 4, ox = tid & 15;
        const int hp0 = (oy + 1) * HS + (ox + 1);
        #pragma unroll
        for (int c = 0; c < CC; c++) o[c] = 0.f;
        #pragma unroll 1
        for (int t = 0; t < 9; t++) {
            const int np = hp0 + (t / 3 - 1) * HS + (t % 3) - 1;
            const ushort* rp = s_x1 + np * SR;
            #pragma unroll
            for (int g = 0; g < 6; g++) {
                uint4 raw = *(const uint4*)(rp + g * 8);
                const uint rr[4] = {raw.x, raw.y, raw.z, raw.w};
                #pragma unroll
                for (int h = 0; h < 4; h++) {
                    float lo = __uint_as_float(rr[h] << 16);
                    float hi = __uint_as_float(rr[h] & 0xFFFF0000u);
                    o[g*8 + 2*h]     = fmaf(lo, w[(g*8 + 2*h) * 27 + 9 + t], o[g*8 + 2*h]);
                    o[g*8 + 2*h + 1] = fmaf(hi, w[(g*8 + 2*h + 1) * 27 + 9 + t], o[g*8 + 2*h + 1]);
                }
            }
        }
    };

    uint qpk[24], kpk[24];

    // ---- q path ----
    stage(evs + (size_t)b * CC * NPIX);
    __syncthreads();
    pw(Wq1);
    __syncthreads();
    {
        float q[CC];
        dw(Wq2, q);
        #pragma unroll
        for (int i = 0; i < 24; i++)
            qpk[i] = (uint)f2bf(q[2*i]) | ((uint)f2bf(q[2*i+1]) << 16);
    }
    // ---- k path (stage img; overlaps with dw-q since they touch different bufs)
    stage(img + (size_t)b * CC * NPIX);
    __syncthreads();
    pw(Wkv1);                      // rows 0..47 of Wkv1 -> k1
    __syncthreads();
    {
        float k[CC];
        dw(Wkv2, k);
        #pragma unroll
        for (int i = 0; i < 24; i++)
            kpk[i] = (uint)f2bf(k[2*i]) | ((uint)f2bf(k[2*i+1]) << 16);
    }
    __syncthreads();               // dw-k done reading s_x1
    // ---- v path (img tile still resident in s_in!) ----
    pw(Wkv1 + CC * CC);            // rows 48..95 -> v1
    __syncthreads();
    {
        float v[CC];
        dw(Wkv2 + CC * 27, v);
        const int oy = tid >> 4, ox = tid & 15;
        const int gy = blockIdx.y * TS + oy, gx = blockIdx.x * TS + ox;
        #pragma unroll
        for (int c = 0; c < CC; c++)
            vout[((size_t)b * CC + c) * NPIX + gy * WW + gx] = v[c];
    }
    __syncthreads();               // all LDS reads done; safe to overwrite

    // ---- Gram reduction: bf16 transpose in LDS + 384 parallel dots ----
    ushort* s_qk = s_mem;          // [96][260]
    #pragma unroll
    for (int i = 0; i < 24; i++) {
        s_qk[(2*i)     * 260 + tid] = (ushort)(qpk[i] & 0xFFFFu);
        s_qk[(2*i + 1) * 260 + tid] = (ushort)(qpk[i] >> 16);
        s_qk[(CC + 2*i)     * 260 + tid] = (ushort)(kpk[i] & 0xFFFFu);
        s_qk[(CC + 2*i + 1) * 260 + tid] = (ushort)(kpk[i] >> 16);
    }
    __syncthreads();

    for (int j = tid; j < 384; j += 256) {
        int ra, rb;
        if (j < 96) { ra = j; rb = j; }
        else {
            int jc = j - 96;
            int c1 = jc / 6;
            int jj = jc - c1 * 6;
            ra = c1;
            rb = CC + (c1 / 6) * 6 + jj;
        }
        const ushort* A  = s_qk + ra * 260;
        const ushort* Bp = s_qk + rb * 260;
        float s = 0.f;
        #pragma unroll 8
        for (int i = 0; i < 256; i += 2) {
            uint a  = *(const uint*)(A + i);
            uint bb = *(const uint*)(Bp + i);
            s = fmaf(__uint_as_float(a << 16),         __uint_as_float(bb << 16),         s);
            s = fmaf(__uint_as_float(a & 0xFFFF0000u), __uint_as_float(bb & 0xFFFF0000u), s);
        }
        float* dst = (j < 48) ? (nq + b * CC + j)
                   : (j < 96) ? (nk + b * CC + (j - 48))
                              : (gram + b * 288 + (j - 96));
        atomicAdd(dst, s);
    }
}

// ---------------------------------------------------------------------------
// K2: logits -> softmax -> fold Wout => M[b][co][c2]  (tiny, one block)
// ---------------------------------------------------------------------------
__global__ void k2_attn(const float* __restrict__ acc_ws,
                        const float* __restrict__ Wout,
                        const float* __restrict__ temp,
                        float* __restrict__ M)
{
    __shared__ float s_attn[2 * 8 * 6 * 6];
    const int tid = threadIdx.x;
    const float* nq   = acc_ws;
    const float* nk   = acc_ws + 96;
    const float* gram = acc_ws + 192;

    if (tid < 16) {
        const int b = tid >> 3, h = tid & 7;
        const float t = temp[h];
        float qn[6], kn[6], L[6][6];
        #pragma unroll
        for (int i = 0; i < 6; i++) {
            qn[i] = fmaxf(sqrtf(nq[b * CC + h * 6 + i]), 1e-12f);
            kn[i] = fmaxf(sqrtf(nk[b * CC + h * 6 + i]), 1e-12f);
        }
        #pragma unroll
        for (int i = 0; i < 6; i++)
            #pragma unroll
            for (int jj = 0; jj < 6; jj++)
                L[i][jj] = gram[b * 288 + (h * 6 + i) * 6 + jj] / (qn[i] * kn[jj]) * t;
        #pragma unroll
        for (int i = 0; i < 6; i++) {
            float m = L[i][0];
            #pragma unroll
            for (int jj = 1; jj < 6; jj++) m = fmaxf(m, L[i][jj]);
            float e[6], ssum = 0.f;
            #pragma unroll
            for (int jj = 0; jj < 6; jj++) { e[jj] = expf(L[i][jj] - m); ssum += e[jj]; }
            #pragma unroll
            for (int jj = 0; jj < 6; jj++)
                s_attn[((b * 8 + h) * 6 + i) * 6 + jj] = e[jj] / ssum;
        }
    }
    __syncthreads();

    for (int e = tid; e < 2 * CC * CC; e += 256) {
        const int b  = e / (CC * CC);
        const int r  = e - b * CC * CC;
        const int co = r / CC;
        const int c2 = r - co * CC;
        const int h2 = c2 / 6, j2 = c2 - h2 * 6;
        float s = 0.f;
        #pragma unroll
        for (int i = 0; i < 6; i++)
            s += Wout[co * CC + h2 * 6 + i] * s_attn[((b * 8 + h2) * 6 + i) * 6 + j2];
        M[e] = s;
    }
}

// ---------------------------------------------------------------------------
// K3: in-place per-pixel out = M @ v  (v lives in d_out)
// ---------------------------------------------------------------------------
__global__ __launch_bounds__(256) void k3_out(float* __restrict__ out,
                                              const float* __restrict__ M)
{
    const int b = blockIdx.y;
    const int pix = blockIdx.x * 256 + threadIdx.x;
    const float* Mb = M + b * CC * CC;
    float* base = out + (size_t)b * CC * NPIX + pix;

    float v[CC];
    #pragma unroll
    for (int c = 0; c < CC; c++) v[c] = base[(size_t)c * NPIX];

    #pragma unroll 1
    for (int co = 0; co < CC; co += 2) {
        float a0 = 0.f, a1 = 0.f, b0 = 0.f, b1 = 0.f;
        #pragma unroll
        for (int ci = 0; ci < CC; ci += 2) {
            a0 = fmaf(Mb[co * CC + ci],           v[ci],     a0);
            a1 = fmaf(Mb[co * CC + ci + 1],       v[ci + 1], a1);
            b0 = fmaf(Mb[(co + 1) * CC + ci],     v[ci],     b0);
            b1 = fmaf(Mb[(co + 1) * CC + ci + 1], v[ci + 1], b1);
        }
        base[(size_t)co * NPIX]       = a0 + a1;
        base[(size_t)(co + 1) * NPIX] = b0 + b1;
    }
}

extern "C" void kernel_launch(void* const* d_in, const int* in_sizes, int n_in,
                              void* d_out, int out_size, void* d_ws, size_t ws_size,
                              hipStream_t stream)
{
    const float* img  = (const float*)d_in[0];
    const float* evs  = (const float*)d_in[1];
    const float* Wq1  = (const float*)d_in[2];
    const float* Wq2  = (const float*)d_in[3];
    const float* Wkv1 = (const float*)d_in[4];
    const float* Wkv2 = (const float*)d_in[5];
    const float* Wout = (const float*)d_in[6];
    const float* temp = (const float*)d_in[7];
    float* out = (float*)d_out;
    float* ws  = (float*)d_ws;

    hipMemsetAsync(ws, 0, 768 * sizeof(float), stream);

    k1_qkv<<<dim3(WW / TS, HH / TS, 2), 256, 0, stream>>>(
        img, evs, Wq1, Wq2, Wkv1, Wkv2, out, ws);
    k2_attn<<<1, 256, 0, stream>>>(ws, Wout, temp, ws + 768);
    k3_out<<<dim3(NPIX / 256, 2), 256, 0, stream>>>(out, ws + 768);
}